// Round 8
// baseline (176.236 us; speedup 1.0000x reference)
//
#include <hip/hip_runtime.h>
#include <math.h>

// Exact IIR reformulation of the 181-tap bi-exponential FIR (see R3-R7).
//   out[n]*scale = r1*(S1[m] - r1^181*S1[m-181]) - r2*S2[m],  m = n+180
//   S[m] = r*S[m-1] + u[m], state zeroed at segment input start.
// R8: multi-task waves with cross-segment prefetch. R3-R7 showed wave
// lifetime ~11us vs ~1.5us critical path: waves idle with ZERO memory
// outstanding ~85% of their life (one 4KB burst at entry). Fix: 8192 waves
// x ~3 independent segments each; while computing segment k (R5's verified
// 2-chunk core, verbatim), segment k+1's 4 float4 are in flight.
// In-flight bytes/CU: ~12KB -> ~128KB. XCD-bijective swizzle for halo L2 reuse.

namespace {
constexpr int kB    = 1000;
constexpr int kT    = 20000;
constexpr int kInW  = kT + 180;       // 20180
constexpr int W     = 180;            // warm-up inputs = taps-1
constexpr int L     = 836;            // outputs per segment; staged 1016 <= 1024
constexpr int SEGS  = 24;             // 24*836 = 20064 >= 20000
constexpr int NTASK = SEGS * kB;      // 24000
constexpr int NBLK  = 2048;           // 8 blocks/CU exactly
constexpr int NWAVE = NBLK * 4;       // 8192
}

struct Coefs {
  float r1e[8], r2e[8];      // r^j, j=0..7
  float s1c[6], s2c[6];      // r^{8*2^i}, i=0..5
  float r1_512;              // r1^512 chunk-carry coeff (r2^512 == 0)
  float A1, A1d, A2;         // r1/scale, r1^182/scale, r2/scale
};

__global__ __launch_bounds__(256, 8)
void biexp_iir_scan(const float* __restrict__ u, float* __restrict__ out, Coefs cf) {
  const int lane = threadIdx.x & 63;

  // XCD-bijective swizzle (2048 = 8*256): each XCD gets contiguous logical
  // blocks -> concurrent waves share segment-halo lines in the same L2.
  const int lbid = (blockIdx.x & 7) * (NBLK >> 3) + (blockIdx.x >> 3);
  const int w    = (lbid << 2) | (threadIdx.x >> 6);    // 0..8191

  // per-lane r^{8*lane} via bit product
  float r1l = 1.f, r2l = 1.f;
  #pragma unroll
  for (int i = 0; i < 6; ++i) {
    r1l *= (lane & (1 << i)) ? cf.s1c[i] : 1.f;
    r2l *= (lane & (1 << i)) ? cf.s2c[i] : 1.f;
  }

  // ---- 4 float4 of one segment tile; addresses clamped (clamped lanes only
  // feed masked stores; garbage only propagates forward to masked elems)
  auto load_task = [&](int t, float4& a0, float4& a1, float4& b0, float4& b1) {
    const int row = t / SEGS;
    const int n0  = (t - row * SEGS) * L;
    const float* ur = u + (size_t)row * kInW;
    int c0 = n0 + 8 * lane;
    c0 = c0 < (kInW - 8) ? c0 : (kInW - 8);
    int c1 = n0 + 512 + 8 * lane;
    c1 = c1 < (kInW - 8) ? c1 : (kInW - 8);
    a0 = *(const float4*)(ur + c0);
    a1 = *(const float4*)(ur + c0 + 4);
    b0 = *(const float4*)(ur + c1);
    b1 = *(const float4*)(ur + c1 + 4);
  };

  // ---- R5's verified 2-chunk scan core, parameterized by task
  auto compute_store = [&](int t, const float4& qa0, const float4& qa1,
                                  const float4& qb0, const float4& qb1) {
    const int row  = t / SEGS;
    const int n0   = (t - row * SEGS) * L;
    const int nend = (n0 + L < kT) ? n0 + L : kT;
    const int lim  = nend - n0 + W;            // exclusive staged bound (mult of 4)
    float* outr = out + (size_t)row * kT;

    float C1 = 0.f, C2 = 0.f;                  // chunk carries
    float pw[8];                               // prev chunk's s1 oct (181-delay)
    #pragma unroll
    for (int j = 0; j < 8; ++j) pw[j] = 0.f;

    #pragma unroll
    for (int c = 0; c < 2; ++c) {
      const float4& qa = c ? qb0 : qa0;
      const float4& qb = c ? qb1 : qa1;
      const float ux[8] = {qa.x, qa.y, qa.z, qa.w, qb.x, qb.y, qb.z, qb.w};

      // in-lane inclusive prefixes (two recurrences interleave)
      float p1[8], p2[8];
      p1[0] = ux[0]; p2[0] = ux[0];
      #pragma unroll
      for (int j = 1; j < 8; ++j) {
        p1[j] = fmaf(cf.r1e[1], p1[j-1], ux[j]);
        p2[j] = fmaf(cf.r2e[1], p2[j-1], ux[j]);
      }

      // cross-lane Hillis scan on oct totals (multiplier r^{8d})
      float S1 = p1[7], S2 = p2[7], t_;
      t_ = __shfl_up(S1, 1);  S1 = lane >= 1  ? fmaf(cf.s1c[0], t_, S1) : S1;
      t_ = __shfl_up(S2, 1);  S2 = lane >= 1  ? fmaf(cf.s2c[0], t_, S2) : S2;
      t_ = __shfl_up(S1, 2);  S1 = lane >= 2  ? fmaf(cf.s1c[1], t_, S1) : S1;
      t_ = __shfl_up(S2, 2);  S2 = lane >= 2  ? fmaf(cf.s2c[1], t_, S2) : S2;
      t_ = __shfl_up(S1, 4);  S1 = lane >= 4  ? fmaf(cf.s1c[2], t_, S1) : S1;
      t_ = __shfl_up(S2, 4);  S2 = lane >= 4  ? fmaf(cf.s2c[2], t_, S2) : S2;
      t_ = __shfl_up(S1, 8);  S1 = lane >= 8  ? fmaf(cf.s1c[3], t_, S1) : S1;
      t_ = __shfl_up(S2, 8);  S2 = lane >= 8  ? fmaf(cf.s2c[3], t_, S2) : S2;
      t_ = __shfl_up(S1, 16); S1 = lane >= 16 ? fmaf(cf.s1c[4], t_, S1) : S1;
      t_ = __shfl_up(S1, 32); S1 = lane >= 32 ? fmaf(cf.s1c[5], t_, S1) : S1;
      // dropped: S2 d=16,32 (r2^128=7.6e-12, r2^256=5.8e-23 << fp32 eps)

      float X1 = __shfl_up(S1, 1); X1 = (lane == 0) ? 0.f : X1;   // exclusive
      float X2 = __shfl_up(S2, 1); X2 = (lane == 0) ? 0.f : X2;
      const float H1 = cf.r1e[1] * fmaf(r1l, C1, X1);
      const float H2 = cf.r2e[1] * fmaf(r2l, C2, X2);

      float s1[8], s2[8];
      #pragma unroll
      for (int j = 0; j < 8; ++j) {
        s1[j] = fmaf(cf.r1e[j], H1, p1[j]);
        s2[j] = fmaf(cf.r2e[j], H2, p2[j]);
      }
      C1 = fmaf(cf.r1_512, C1, __shfl(S1, 63));
      C2 = __shfl(S2, 63);                    // r2^512 == 0

      // delayed S1[e-181]: slot (j<5 ? j+3 : j-5), rot (j<5 ? 23 : 22);
      // low lanes source prev chunk's oct (pw)
      float y[8];
      #pragma unroll
      for (int j = 0; j < 8; ++j) {
        const int slot = (j < 5) ? j + 3 : j - 5;
        const int rot  = (j < 5) ? 23 : 22;
        const float z  = (lane <= 63 - rot) ? s1[slot] : pw[slot];
        const float d  = __shfl(z, (lane - rot) & 63);
        y[j] = fmaf(-cf.A2, s2[j], fmaf(-cf.A1d, d, cf.A1 * s1[j]));
      }
      #pragma unroll
      for (int j = 0; j < 8; ++j) pw[j] = s1[j];

      // stores: float4-granular masks (W, lim mult of 4)
      const int off0 = (c << 9) + 8 * lane;
      if (off0 >= W && off0 < lim) {
        float4 v; v.x = y[0]; v.y = y[1]; v.z = y[2]; v.w = y[3];
        *(float4*)(outr + (n0 - W + off0)) = v;
      }
      if (off0 + 4 >= W && off0 + 4 < lim) {
        float4 v; v.x = y[4]; v.y = y[5]; v.z = y[6]; v.w = y[7];
        *(float4*)(outr + (n0 - W + off0 + 4)) = v;
      }
    }
  };

  // ---- task pipeline: compute(t) runs with t+NWAVE's loads in flight
  int t = w;                                   // w < 8192 < NTASK: always valid
  float4 A0, A1v, B0, B1;
  load_task(t, A0, A1v, B0, B1);

  #pragma unroll
  for (int i = 0; i < 3; ++i) {
    if (i > 0 && t >= NTASK) break;            // wave-uniform tail exit
    const int tn = t + NWAVE;
    float4 P0, P1, P2, P3;
    if (i < 2) {
      const int tl = (tn < NTASK) ? tn : t;    // clamp: harmless re-load for tail waves
      load_task(tl, P0, P1, P2, P3);
      __builtin_amdgcn_sched_barrier(0);       // pin prefetch issue before compute
    }
    compute_store(t, A0, A1v, B0, B1);         // waits vmcnt(4): own tile only
    if (i < 2) { A0 = P0; A1v = P1; B0 = P2; B1 = P3; t = tn; }
  }
}

extern "C" void kernel_launch(void* const* d_in, const int* in_sizes, int n_in,
                              void* d_out, int out_size, void* d_ws, size_t ws_size,
                              hipStream_t stream) {
  const float* u = (const float*)d_in[0];
  float* out = (float*)d_out;

  const double r1 = exp(-1.0 / 30.0);
  const double r2 = exp(-1.0 / 5.0);
  const double scale = pow(6.0, -5.0 / 25.0) - pow(6.0, -30.0 / 25.0);

  Coefs cf;
  for (int j = 0; j < 8; ++j) {
    cf.r1e[j] = (float)pow(r1, (double)j);
    cf.r2e[j] = (float)pow(r2, (double)j);
  }
  for (int i = 0; i < 6; ++i) {
    cf.s1c[i] = (float)pow(r1, (double)(8 << i));
    cf.s2c[i] = (float)pow(r2, (double)(8 << i));
  }
  cf.r1_512 = (float)pow(r1, 512.0);
  cf.A1  = (float)(r1 / scale);
  cf.A1d = (float)(pow(r1, 182.0) / scale);
  cf.A2  = (float)(r2 / scale);

  hipLaunchKernelGGL(biexp_iir_scan, dim3(NBLK), dim3(256, 1, 1), 0, stream,
                     u, out, cf);
}

// Round 9
// 173.276 us; speedup vs baseline: 1.0171x; 1.0171x over previous
//
#include <hip/hip_runtime.h>
#include <math.h>

// Exact IIR reformulation of the 181-tap bi-exponential FIR (see R3-R8).
//   out[n]*scale = r1*(S1[m] - r1^181*S1[m-181]) - r2*S2[m],  m = n+180
//   S[m] = r*S[m-1] + u[m], state zeroed at segment input start.
// R9: single-generation grid + rolling per-wave task pipeline.
//  - 24000 tasks, 3 consecutive segments per wave -> 8000 waves = 2000 blocks
//    <= 2048 resident capacity: every wave resident for the whole kernel.
//  - loads T0+T1 at entry (8 f4 in flight), T2's loads issued after T0's
//    compute: memory stays busy during all compute phases.
//  - R8 bugs removed: no sched_barrier (spill), no strided task order
//    (locality), no tail re-load (K divides SEGS exactly).
//  - compute core = R5's verified 2-chunk scan, verbatim.

namespace {
constexpr int kB    = 1000;
constexpr int kT    = 20000;
constexpr int kInW  = kT + 180;       // 20180
constexpr int W     = 180;            // warm-up inputs = taps-1
constexpr int L     = 836;            // outputs per segment; staged 1016 <= 1024
constexpr int SEGS  = 24;             // 24*836 = 20064 >= 20000
constexpr int K     = 3;              // consecutive segments per wave
constexpr int NWAVE = kB * SEGS / K;  // 8000
constexpr int NBLK  = NWAVE / 4;      // 2000 blocks -> <= 8/CU, all resident
}

struct Coefs {
  float r1e[8], r2e[8];      // r^j, j=0..7
  float s1c[6], s2c[6];      // r^{8*2^i}, i=0..5
  float r1_512;              // r1^512 chunk-carry coeff (r2^512 == 0)
  float A1, A1d, A2;         // r1/scale, r1^182/scale, r2/scale
};

__global__ __launch_bounds__(256, 8)
void biexp_iir_scan(const float* __restrict__ u, float* __restrict__ out, Coefs cf) {
  const int lane = threadIdx.x & 63;
  const int w    = (blockIdx.x << 2) | (threadIdx.x >> 6);   // 0..7999
  const int row  = w >> 3;                                   // 0..999
  const int seg0 = (w & 7) * K;                              // 0,3,..,21

  const float* ur = u + (size_t)row * kInW;
  float* outr = out + (size_t)row * kT;

  // per-lane r^{8*lane} via bit product
  float r1l = 1.f, r2l = 1.f;
  #pragma unroll
  for (int i = 0; i < 6; ++i) {
    r1l *= (lane & (1 << i)) ? cf.s1c[i] : 1.f;
    r2l *= (lane & (1 << i)) ? cf.s2c[i] : 1.f;
  }

  // 4 float4 of one segment tile; clamped lanes only feed masked stores
  auto load_tile = [&](int n0, float4& a0, float4& a1, float4& b0, float4& b1) {
    int c0 = n0 + 8 * lane;
    c0 = c0 < (kInW - 8) ? c0 : (kInW - 8);
    int c1 = n0 + 512 + 8 * lane;
    c1 = c1 < (kInW - 8) ? c1 : (kInW - 8);
    a0 = *(const float4*)(ur + c0);
    a1 = *(const float4*)(ur + c0 + 4);
    b0 = *(const float4*)(ur + c1);
    b1 = *(const float4*)(ur + c1 + 4);
  };

  // R5's verified 2-chunk scan core (carries/pw local per task)
  auto seg_compute = [&](int n0, const float4& qa0, const float4& qa1,
                                 const float4& qb0, const float4& qb1) {
    const int nend = (n0 + L < kT) ? n0 + L : kT;
    const int lim  = nend - n0 + W;            // exclusive staged bound (mult of 4)

    float C1 = 0.f, C2 = 0.f;
    float pw[8];
    #pragma unroll
    for (int j = 0; j < 8; ++j) pw[j] = 0.f;

    #pragma unroll
    for (int c = 0; c < 2; ++c) {
      const float4& qa = c ? qb0 : qa0;
      const float4& qb = c ? qb1 : qa1;
      const float ux[8] = {qa.x, qa.y, qa.z, qa.w, qb.x, qb.y, qb.z, qb.w};

      float p1[8], p2[8];
      p1[0] = ux[0]; p2[0] = ux[0];
      #pragma unroll
      for (int j = 1; j < 8; ++j) {
        p1[j] = fmaf(cf.r1e[1], p1[j-1], ux[j]);
        p2[j] = fmaf(cf.r2e[1], p2[j-1], ux[j]);
      }

      float S1 = p1[7], S2 = p2[7], t_;
      t_ = __shfl_up(S1, 1);  S1 = lane >= 1  ? fmaf(cf.s1c[0], t_, S1) : S1;
      t_ = __shfl_up(S2, 1);  S2 = lane >= 1  ? fmaf(cf.s2c[0], t_, S2) : S2;
      t_ = __shfl_up(S1, 2);  S1 = lane >= 2  ? fmaf(cf.s1c[1], t_, S1) : S1;
      t_ = __shfl_up(S2, 2);  S2 = lane >= 2  ? fmaf(cf.s2c[1], t_, S2) : S2;
      t_ = __shfl_up(S1, 4);  S1 = lane >= 4  ? fmaf(cf.s1c[2], t_, S1) : S1;
      t_ = __shfl_up(S2, 4);  S2 = lane >= 4  ? fmaf(cf.s2c[2], t_, S2) : S2;
      t_ = __shfl_up(S1, 8);  S1 = lane >= 8  ? fmaf(cf.s1c[3], t_, S1) : S1;
      t_ = __shfl_up(S2, 8);  S2 = lane >= 8  ? fmaf(cf.s2c[3], t_, S2) : S2;
      t_ = __shfl_up(S1, 16); S1 = lane >= 16 ? fmaf(cf.s1c[4], t_, S1) : S1;
      t_ = __shfl_up(S1, 32); S1 = lane >= 32 ? fmaf(cf.s1c[5], t_, S1) : S1;
      // dropped: S2 d=16,32 (r2^128=7.6e-12, r2^256=5.8e-23 << fp32 eps)

      float X1 = __shfl_up(S1, 1); X1 = (lane == 0) ? 0.f : X1;
      float X2 = __shfl_up(S2, 1); X2 = (lane == 0) ? 0.f : X2;
      const float H1 = cf.r1e[1] * fmaf(r1l, C1, X1);
      const float H2 = cf.r2e[1] * fmaf(r2l, C2, X2);

      float s1[8], s2[8];
      #pragma unroll
      for (int j = 0; j < 8; ++j) {
        s1[j] = fmaf(cf.r1e[j], H1, p1[j]);
        s2[j] = fmaf(cf.r2e[j], H2, p2[j]);
      }
      C1 = fmaf(cf.r1_512, C1, __shfl(S1, 63));
      C2 = __shfl(S2, 63);                    // r2^512 == 0

      float y[8];
      #pragma unroll
      for (int j = 0; j < 8; ++j) {
        const int slot = (j < 5) ? j + 3 : j - 5;
        const int rot  = (j < 5) ? 23 : 22;
        const float z  = (lane <= 63 - rot) ? s1[slot] : pw[slot];
        const float d  = __shfl(z, (lane - rot) & 63);
        y[j] = fmaf(-cf.A2, s2[j], fmaf(-cf.A1d, d, cf.A1 * s1[j]));
      }
      #pragma unroll
      for (int j = 0; j < 8; ++j) pw[j] = s1[j];

      const int off0 = (c << 9) + 8 * lane;
      if (off0 >= W && off0 < lim) {
        float4 v; v.x = y[0]; v.y = y[1]; v.z = y[2]; v.w = y[3];
        *(float4*)(outr + (n0 - W + off0)) = v;
      }
      if (off0 + 4 >= W && off0 + 4 < lim) {
        float4 v; v.x = y[4]; v.y = y[5]; v.z = y[6]; v.w = y[7];
        *(float4*)(outr + (n0 - W + off0 + 4)) = v;
      }
    }
  };

  // ---- rolling 3-task pipeline over consecutive segments (straight-line)
  const int n0_0 = (seg0    ) * L;
  const int n0_1 = (seg0 + 1) * L;
  const int n0_2 = (seg0 + 2) * L;

  float4 A0, A1v, A2v, A3;      // tile T0 (reused for T2)
  float4 B0, B1, B2, B3;        // tile T1
  load_tile(n0_0, A0, A1v, A2v, A3);
  load_tile(n0_1, B0, B1, B2, B3);

  seg_compute(n0_0, A0, A1v, A2v, A3);        // waits own vmcnt; T1 in flight
  load_tile(n0_2, A0, A1v, A2v, A3);          // T2 issued under T1's compute
  seg_compute(n0_1, B0, B1, B2, B3);
  seg_compute(n0_2, A0, A1v, A2v, A3);
}

extern "C" void kernel_launch(void* const* d_in, const int* in_sizes, int n_in,
                              void* d_out, int out_size, void* d_ws, size_t ws_size,
                              hipStream_t stream) {
  const float* u = (const float*)d_in[0];
  float* out = (float*)d_out;

  const double r1 = exp(-1.0 / 30.0);
  const double r2 = exp(-1.0 / 5.0);
  const double scale = pow(6.0, -5.0 / 25.0) - pow(6.0, -30.0 / 25.0);

  Coefs cf;
  for (int j = 0; j < 8; ++j) {
    cf.r1e[j] = (float)pow(r1, (double)j);
    cf.r2e[j] = (float)pow(r2, (double)j);
  }
  for (int i = 0; i < 6; ++i) {
    cf.s1c[i] = (float)pow(r1, (double)(8 << i));
    cf.s2c[i] = (float)pow(r2, (double)(8 << i));
  }
  cf.r1_512 = (float)pow(r1, 512.0);
  cf.A1  = (float)(r1 / scale);
  cf.A1d = (float)(pow(r1, 182.0) / scale);
  cf.A2  = (float)(r2 / scale);

  hipLaunchKernelGGL(biexp_iir_scan, dim3(NBLK), dim3(256, 1, 1), 0, stream,
                     u, out, cf);
}